// Round 16
// baseline (263.560 us; speedup 1.0000x reference)
//
#include <hip/hip_runtime.h>
#include <math.h>

typedef __bf16 bf16;
typedef __bf16 bf16x8 __attribute__((ext_vector_type(8)));
typedef __bf16 bf16x4 __attribute__((ext_vector_type(4)));
typedef float f32x2 __attribute__((ext_vector_type(2)));
typedef float f32x4 __attribute__((ext_vector_type(4)));
typedef float f32x16 __attribute__((ext_vector_type(16)));
typedef unsigned int uint;
typedef uint u32x4 __attribute__((ext_vector_type(4)));
typedef uint u32x2 __attribute__((ext_vector_type(2)));
typedef __bf16 bf16x8_a __attribute__((ext_vector_type(8), __may_alias__));
typedef uint u32x2_a __attribute__((ext_vector_type(2), __may_alias__));
typedef __bf16 bf16x4_a __attribute__((ext_vector_type(4), __may_alias__));
typedef __bf16 bf16_a __attribute__((__may_alias__));

constexpr int BATCH = 2;
constexpr int SEQ   = 2048;
constexpr int HID   = 2048;
constexpr int NHEAD = 16;
constexpr int NKV   = 8;
constexpr int HD    = 128;
constexpr int MROWS = BATCH * SEQ; // 4096

#define DEVINL __device__ __forceinline__

// raw barrier with compiler reorder fence (no implicit vmcnt/lgkm drain)
#define BAR()                                 \
  do {                                        \
    asm volatile("" ::: "memory");            \
    __builtin_amdgcn_s_barrier();             \
    asm volatile("" ::: "memory");            \
  } while (0)

#define WAITV(N) asm volatile("s_waitcnt vmcnt(" #N ")" ::: "memory")

DEVINL void async16(void* l, const void* g) {
  __builtin_amdgcn_global_load_lds((const __attribute__((address_space(1))) void*)g,
                                   (__attribute__((address_space(3))) void*)l, 16, 0, 0);
}

DEVINL f32x4 mfma16(bf16x8 a, bf16x8 b, f32x4 c) {
  return __builtin_amdgcn_mfma_f32_16x16x32_bf16(a, b, c, 0, 0, 0);
}
DEVINL f32x16 mfma32(bf16x8 a, bf16x8 b, f32x16 c) {
  return __builtin_amdgcn_mfma_f32_32x32x16_bf16(a, b, c, 0, 0, 0);
}

DEVINL f32x4 fzero4() { f32x4 z; z[0] = 0.f; z[1] = 0.f; z[2] = 0.f; z[3] = 0.f; return z; }

DEVINL float ex2(float x) {
#if __has_builtin(__builtin_amdgcn_exp2f)
  return __builtin_amdgcn_exp2f(x);
#else
  return __expf(x * 0.6931471805599453f);
#endif
}

DEVINL uint pkbf16(float lo, float hi) {
  unsigned short l = __builtin_bit_cast(unsigned short, (bf16)lo);
  unsigned short h = __builtin_bit_cast(unsigned short, (bf16)hi);
  return (uint)l | ((uint)h << 16);
}

// hardware half-wave swap: returns {.x = {a.lo, b.lo}, .y = {a.hi, b.hi}}
DEVINL u32x2 pswap(uint a, uint b) {
#if __has_builtin(__builtin_amdgcn_permlane32_swap)
  return __builtin_amdgcn_permlane32_swap(a, b, false, false);
#else
  int hl = (int)((threadIdx.x >> 5) & 1);
  uint as = __shfl_xor(a, 32), bs = __shfl_xor(b, 32);
  u32x2 r;
  r[0] = hl ? bs : a;  // {a.lo, b.lo}
  r[1] = hl ? b : as;  // {a.hi, b.hi}
  return r;
#endif
}

// ---------------- fused prep: W transposes (z=0..3), rope tables (z=4), X cast (z=5) ----
__global__ __launch_bounds__(256) void prep(const float* __restrict__ X,
                                            const float* __restrict__ Wq,
                                            const float* __restrict__ Wk,
                                            const float* __restrict__ Wv,
                                            const float* __restrict__ Wo,
                                            bf16* __restrict__ Xb,
                                            bf16* __restrict__ WqT, bf16* __restrict__ WkT,
                                            bf16* __restrict__ WvT, bf16* __restrict__ WoT,
                                            float* __restrict__ ct, float* __restrict__ st) {
  const int tid = threadIdx.x;
  const int z = blockIdx.z;
  if (z == 4) {
    int idx = (blockIdx.y * 32 + blockIdx.x) * 256 + tid;
    if (idx < SEQ * 64) {
      int s = idx >> 6, d = idx & 63;
      float freq = powf(10000.0f, -(float)d * (1.0f / 64.0f));
      float a = (float)s * freq;
      ct[idx] = cosf(a);
      st[idx] = sinf(a);
    }
    return;
  }
  if (z == 5) {
    int j = (blockIdx.y * 32 + blockIdx.x) * 256 + tid;
#pragma unroll
    for (int it = 0; it < 8; it++) {
      int e = (it * 262144 + j) * 4;
      float4 v = *(const float4*)(X + e);
      bf16x4 o;
      o[0] = (bf16)v.x; o[1] = (bf16)v.y; o[2] = (bf16)v.z; o[3] = (bf16)v.w;
      *(bf16x4*)(Xb + e) = o;
    }
    return;
  }
  __shared__ bf16 t[64][65];
  const float* W; bf16* WT; int N;
  switch (z) {
    case 0: W = Wq; WT = WqT; N = 2048; break;
    case 1: W = Wk; WT = WkT; N = 1024; break;
    case 2: W = Wv; WT = WvT; N = 1024; break;
    default: W = Wo; WT = WoT; N = 2048; break;
  }
  int n0 = blockIdx.x * 64, k0 = blockIdx.y * 64;
  if (n0 >= N) return;
#pragma unroll
  for (int p = 0; p < 4; p++) {
    int r = (tid >> 4) + p * 16;
    int c4 = (tid & 15) * 4;
    float4 v = *(const float4*)(&W[(size_t)(k0 + r) * N + n0 + c4]);
    t[r][c4 + 0] = (bf16)v.x;
    t[r][c4 + 1] = (bf16)v.y;
    t[r][c4 + 2] = (bf16)v.z;
    t[r][c4 + 3] = (bf16)v.w;
  }
  __syncthreads();
#pragma unroll
  for (int p = 0; p < 4; p++) {
    int nr = (tid >> 4) + p * 16;
    int kb = (tid & 15) * 4;
    bf16x4 o;
    o[0] = t[kb + 0][nr];
    o[1] = t[kb + 1][nr];
    o[2] = t[kb + 2][nr];
    o[3] = t[kb + 3][nr];
    *(bf16x4_a*)(&WT[(size_t)(n0 + nr) * 2048 + k0 + kb]) = o;
  }
}

// ---------------- V[b*S+s][kvh*128+d] -> VT[(b*8+kvh)*128+d][s] ----------------
__global__ __launch_bounds__(256) void vtrans(const bf16* __restrict__ V, bf16* __restrict__ VT) {
  __shared__ bf16 t[64][65];
  int s0 = blockIdx.x * 64, d0 = blockIdx.y * 64;
  int bh = blockIdx.z, b = bh >> 3, kvh = bh & 7;
  for (int i = threadIdx.x; i < 4096; i += 256) {
    int r = i >> 6, c = i & 63;
    t[r][c] = V[(size_t)(b * SEQ + s0 + r) * (NKV * HD) + kvh * HD + d0 + c];
  }
  __syncthreads();
  for (int i = threadIdx.x; i < 4096; i += 256) {
    int r = i >> 6, c = i & 63;
    VT[((size_t)bh * HD + d0 + r) * SEQ + s0 + c] = t[c][r];
  }
}

// ================= 128x128-tile m97-style fused QKV GEMM =================
// 256 thr / 4 waves; wave = 32 rows x 128 cols; single-buffered 32 KB LDS;
// per K-tile: {BAR; stage A+B (8 gload_lds); vmcnt(0); BAR; 32 MFMA}.
// 1024 WGs -> 4 blocks/CU: cross-block TLP fills barrier/latency stalls (m97/m114).
// Epilogue: RoPE (cols<3072) + Q pre-scale (cols<2048), split outputs Q/K/V.
__global__ __launch_bounds__(256) void gemmA(const bf16* __restrict__ A,
                                             const bf16* __restrict__ BT,
                                             bf16* __restrict__ C0, bf16* __restrict__ C1,
                                             bf16* __restrict__ C2, int K,
                                             const float* __restrict__ ct,
                                             const float* __restrict__ st) {
  __shared__ alignas(16) char ldsA[16384];  // [128 r][64 k] bf16, 8-slot XOR swizzle
  __shared__ alignas(16) char ldsB[16384];
  const int tid = threadIdx.x, lane = tid & 63, w = tid >> 6;
  const int l15 = lane & 15, l4 = lane >> 4;
  const int gx = 32;  // N=4096 / 128
  const int nwg = gx * gridDim.y;  // 1024
  int id = blockIdx.y * gx + blockIdx.x;
  id = (id & 7) * (nwg >> 3) + (id >> 3);
  const int row0 = (id / gx) * 128;
  const int col0 = (id % gx) * 128;

  f32x4 acc[2][8];
#pragma unroll
  for (int mt = 0; mt < 2; mt++)
#pragma unroll
    for (int nt = 0; nt < 8; nt++) acc[mt][nt] = fzero4();

  const bf16* Asrc = A + (size_t)row0 * K;
  const bf16* Bsrc = BT + (size_t)col0 * K;
  const int nk = K >> 6;

  for (int t = 0; t < nk; ++t) {
    const int k0 = t << 6;
    BAR();  // all waves' reads of previous tile done -> safe to overwrite
#pragma unroll
    for (int j = 0; j < 4; j++) {
      int ci = j * 256 + tid;
      int r = ci >> 3, ps = ci & 7, ls = ps ^ (r & 7);
      async16(ldsA + ci * 16, Asrc + (size_t)r * K + k0 + ls * 8);
      async16(ldsB + ci * 16, Bsrc + (size_t)r * K + k0 + ls * 8);
    }
    WAITV(0);
    BAR();  // staged tile visible to all waves

    bf16x8 af[2][2];
#pragma unroll
    for (int mt = 0; mt < 2; mt++)
#pragma unroll
      for (int kc = 0; kc < 2; kc++) {
        int r = w * 32 + mt * 16 + l15;
        int off = ((r << 7) + ((kc * 4 + l4) << 4)) ^ ((r & 7) << 4);
        af[mt][kc] = *(const bf16x8_a*)(ldsA + off);
      }
#pragma unroll
    for (int nt = 0; nt < 8; nt++) {
#pragma unroll
      for (int kc = 0; kc < 2; kc++) {
        int c = nt * 16 + l15;
        int off = ((c << 7) + ((kc * 4 + l4) << 4)) ^ ((c & 7) << 4);
        bf16x8 bfr = *(const bf16x8_a*)(ldsB + off);
        acc[0][nt] = mfma16(af[0][kc], bfr, acc[0][nt]);
        acc[1][nt] = mfma16(af[1][kc], bfr, acc[1][nt]);
      }
    }
  }

  // ---- epilogue: RoPE + split store (cols head-aligned: col0 % 128 == 0) ----
#pragma unroll
  for (int mt = 0; mt < 2; mt++)
#pragma unroll
    for (int nt = 0; nt < 8; nt++)
#pragma unroll
      for (int rg = 0; rg < 4; rg++) {
        int row = row0 + w * 32 + mt * 16 + l4 * 4 + rg;
        int cl = col0 + nt * 16 + l15;
        float v = acc[mt][nt][rg];
        if (cl < 3072) {  // RoPE for Q and K ranges
          int s = row & (SEQ - 1);
          int ntp = (nt < 4) ? nt + 4 : nt - 4;  // pair col +/- 64 within same lane
          float pv = (nt < 4) ? -acc[mt][ntp][rg] : acc[mt][ntp][rg];
          float cc = ct[s * 64 + (cl & 63)];
          float ss = st[s * 64 + (cl & 63)];
          v = fmaf(v, cc, pv * ss);
        }
        if (cl < 2048) {
          v *= 1.7677669529663689e-3f;  // pre-scale Q by 1/(50*sqrt(128))
          C0[(size_t)row * 2048 + cl] = (bf16)v;
        } else if (cl < 3072) {
          C1[(size_t)row * 1024 + (cl - 2048)] = (bf16)v;
        } else {
          C2[(size_t)row * 1024 + (cl - 3072)] = (bf16)v;
        }
      }
}

// ================= 256x128 GEMM (Wo) — merged 1-phase/tile (unchanged from R15) =========
__global__ __launch_bounds__(512, 2) void gemm2p(const bf16* __restrict__ A,
                                                 const bf16* __restrict__ BT,
                                                 float* __restrict__ C, int M, int N, int K) {
  __shared__ alignas(16) char ldsA[65536];  // [buf:2][half:2][128r][64k]
  __shared__ alignas(16) char ldsB[49152];  // [buf:3][128c][64k]
  const int tid = threadIdx.x, lane = tid & 63, w = tid >> 6;
  const int l15 = lane & 15, l4 = lane >> 4;
  const int wm = w >> 1, wn = w & 1;
  const int gx = gridDim.x;
  const int nwg = gx * gridDim.y;
  int id = blockIdx.y * gx + blockIdx.x;
  id = (id & 7) * (nwg >> 3) + (id >> 3);
  const int row0 = (id / gx) * 256;
  const int col0 = (id % gx) * 128;

  f32x4 acc[4][4];
#pragma unroll
  for (int mt = 0; mt < 4; mt++)
#pragma unroll
    for (int nt = 0; nt < 4; nt++) acc[mt][nt] = fzero4();

  const int rG0 = tid >> 3, sG0 = ((tid & 7) ^ (rG0 & 7)) * 8;
  const int ci1 = 512 + tid;
  const int rG1 = ci1 >> 3, sG1 = ((ci1 & 7) ^ (rG1 & 7)) * 8;
  const int dst0 = tid * 16, dst1 = (512 + tid) * 16;

  const bf16* Asrc = A + (size_t)row0 * K;
  const bf16* Bsrc = BT + (size_t)col0 * K;
  const int nk = K >> 6;

#define STG_A2(half, kt, buf)                                        \
  {                                                                  \
    char* d = ldsA + (buf) * 32768 + (half) * 16384;                 \
    const bf16* s = Asrc + (size_t)((half) * 128) * K + (kt) * 64;   \
    async16(d + dst0, s + (size_t)rG0 * K + sG0);                    \
    async16(d + dst1, s + (size_t)rG1 * K + sG1);                    \
  }
#define STG_B2(kt, buf)                                              \
  {                                                                  \
    char* d = ldsB + (buf) * 16384;                                  \
    const bf16* s = Bsrc + (kt) * 64;                                \
    async16(d + dst0, s + (size_t)rG0 * K + sG0);                    \
    async16(d + dst1, s + (size_t)rG1 * K + sG1);                    \
  }

  STG_B2(0, 0) STG_A2(0, 0, 0) STG_A2(1, 0, 0)
  STG_B2(1, 1) STG_A2(0, 1, 1) STG_A2(1, 1, 1)
  WAITV(6);
  BAR();

  bf16x8 af[8];
  bf16x8 bfr[8];

  for (int t = 0; t < nk; ++t) {
    const int abuf = t & 1;
    int bb = t % 3;
    const char* bA = ldsA + abuf * 32768 + (wm >> 1) * 16384;
    const char* bB = ldsB + bb * 16384;
    const bool s2 = (t + 2) < nk;
    int bb2 = bb + 2; if (bb2 >= 3) bb2 -= 3;

#pragma unroll
    for (int mt = 0; mt < 4; mt++)
#pragma unroll
      for (int kc = 0; kc < 2; kc++) {
        int r = (wm & 1) * 64 + mt * 16 + l15;
        int off = ((r << 7) + ((kc * 4 + l4) << 4)) ^ ((r & 7) << 4);
        af[mt * 2 + kc] = *(const bf16x8_a*)(bA + off);
      }
#pragma unroll
    for (int nt = 0; nt < 4; nt++)
#pragma unroll
      for (int kc = 0; kc < 2; kc++) {
        int c = wn * 16 + nt * 32 + l15;
        int off = ((c << 7) + ((kc * 4 + l4) << 4)) ^ ((c & 7) << 4);
        bfr[nt * 2 + kc] = *(const bf16x8_a*)(bB + off);
      }
    BAR();  // all waves' reads done -> safe to stage into abuf
    if (s2) { STG_B2(t + 2, bb2) STG_A2(0, t + 2, abuf) STG_A2(1, t + 2, abuf) }
    __builtin_amdgcn_s_setprio(1);
#pragma unroll
    for (int mt = 0; mt < 4; mt++)
#pragma unroll
      for (int nt = 0; nt < 4; nt++)
#pragma unroll
        for (int kc = 0; kc < 2; kc++)
          acc[mt][nt] = mfma16(af[mt * 2 + kc], bfr[nt * 2 + kc], acc[mt][nt]);
    __builtin_amdgcn_s_setprio(0);
    if (s2) { WAITV(6); } else { WAITV(0); }
    BAR();
  }
#undef STG_A2
#undef STG_B2

#pragma unroll
  for (int mt = 0; mt < 4; mt++)
#pragma unroll
    for (int nt = 0; nt < 4; nt++)
#pragma unroll
      for (int rg = 0; rg < 4; rg++) {
        int row = row0 + wm * 64 + mt * 16 + l4 * 4 + rg;
        int cl = col0 + wn * 16 + nt * 32 + l15;
        C[(size_t)row * N + cl] = acc[mt][nt][rg];
      }
}

// ========== Flash attention v10 (unchanged from R14, race-free) ==========
__global__ __launch_bounds__(512, 2) void attn10(const bf16* __restrict__ Q,
                                                 const bf16* __restrict__ Kg,
                                                 const bf16* __restrict__ VTg,
                                                 bf16* __restrict__ O) {
  __shared__ alignas(16) char ldsK[49152];   // 3 x [64 kv][128 d], 16-slot swizzle
  __shared__ alignas(16) char ldsV[49152];   // 3 x [128 d][64 kv], 8-slot swizzle
  const int tid = threadIdx.x, lane = tid & 63, w = tid >> 6;
  const int l31 = lane & 31, hl = lane >> 5;

  const int nx = gridDim.x, ny = gridDim.y;
  const int nwg = nx * ny * gridDim.z;  // 256
  int id = (blockIdx.z * ny + blockIdx.y) * nx + blockIdx.x;
  id = (id & 7) * (nwg >> 3) + (id >> 3);
  const int qt = id % nx; id /= nx;
  const int h = id % ny; const int b = id / ny;
  const int kvh = h >> 1;
  const int qrow = b * SEQ + qt * 256 + w * 32 + l31;

  bf16x8 qf[8];
  const bf16* qp = Q + (size_t)qrow * (NHEAD * HD) + h * HD + hl * 8;
#pragma unroll
  for (int kc = 0; kc < 8; kc++) qf[kc] = *(const bf16x8_a*)(qp + kc * 16);

  f32x16 oT[4];
#pragma unroll
  for (int dt = 0; dt < 4; dt++)
#pragma unroll
    for (int r = 0; r < 16; r++) oT[dt][r] = 0.f;
  f32x2 ls2; ls2[0] = 0.f; ls2[1] = 0.f;

  const int rK = tid >> 4, sK = (tid & 15) ^ (rK & 15);  // 16-slot swizzle
  const int rV = tid >> 3, sV = (tid & 7) ^ (rV & 7);    // 8-slot swizzle
  const size_t koff0 = (size_t)(b * SEQ + rK) * (NKV * HD) + kvh * HD + sK * 8;
  const size_t voff0 = ((size_t)(b * NKV + kvh) * HD + rV) * SEQ + sV * 8;

  const float Ac = 72.13475204444817f;    // 50*log2(e)
  const float Bc = -24.044917348149389f;  // Ac * (-1/3)

  auto STAGE = [&](int buf, int t) {
    char* dK = ldsK + buf * 16384;
    char* dV = ldsV + buf * 16384;
    const bf16* ks = Kg + koff0 + (size_t)t * (64 * NKV * HD);
    const bf16* vs = VTg + voff0 + (size_t)t * 64;
    async16(dK + tid * 16, ks);
    async16(dK + (512 + tid) * 16, ks + (size_t)32 * (NKV * HD));
    async16(dV + tid * 16, vs);
    async16(dV + (512 + tid) * 16, vs + (size_t)64 * SEQ);
  };

  const int kvr0 = l31, kvr1 = 32 + l31;

#define QKT(SC, lKp)                                                     \
  do {                                                                   \
    _Pragma("unroll")                                                    \
    for (int r = 0; r < 16; r++) { (SC)[0][r] = 0.f; (SC)[1][r] = 0.f; } \
    _Pragma("unroll")                                                    \
    for (int kc = 0; kc < 8; kc++) {                                     \
      int slot = kc * 2 + hl;                                            \
      int off0 = (kvr0 << 8) | ((slot ^ (kvr0 & 15)) << 4);              \
      int off1 = (kvr1 << 8) | ((slot ^ (kvr1 & 15)) << 4);              \
      bf16x8 kf0 = *(const bf16x8_a*)((lKp) + off0);                     \
      bf16x8 kf1 = *(const bf16x8_a*)((lKp) + off1);                     \
      (SC)[0] = mfma32(kf0, qf[kc], (SC)[0]);                            \
      (SC)[1] = mfma32(kf1, qf[kc], (SC)[1]);                            \
    }                                                                    \
  } while (0)

#define SOFTMAX(SC, PB)                                                  \
  do {                                                                   \
    _Pragma("unroll")                                                    \
    for (int ntb = 0; ntb < 2; ntb++) {                                  \
      uint u[4][2];                                                      \
      _Pragma("unroll")                                                  \
      for (int r2 = 0; r2 < 8; r2++) {                                   \
        f32x2 z; z[0] = (SC)[ntb][2 * r2]; z[1] = (SC)[ntb][2 * r2 + 1]; \
        f32x2 z2 = z * z;                                                \
        f32x2 wv = z2 * Bc + Ac;                                         \
        f32x2 e = z * wv;                                                \
        float p0 = ex2(e[0]), p1 = ex2(e[1]);                            \
        ls2[0] += p0; ls2[1] += p1;                                      \
        u[r2 >> 1][r2 & 1] = pkbf16(p0, p1);                             \
      }                                                                  \
      _Pragma("unroll")                                                  \
      for (int sub = 0; sub < 2; sub++) {                                \
        u32x2 r0 = pswap(u[2 * sub][0], u[2 * sub + 1][0]);              \
        u32x2 r1 = pswap(u[2 * sub][1], u[2 * sub + 1][1]);              \
        u32x4 bu;                                                        \
        bu[0] = r0[0];                                                   \
        bu[1] = r1[0];                                                   \
        bu[2] = r0[1];                                                   \
        bu[3] = r1[1];                                                   \
        (PB)[ntb * 2 + sub] = __builtin_bit_cast(bf16x8, bu);            \
      }                                                                  \
    }                                                                    \
  } while (0)

#define PVACC(PB, lVp)                                                   \
  do {                                                                   \
    _Pragma("unroll")                                                    \
    for (int kvb = 0; kvb < 4; kvb++) {                                  \
      int slot = kvb * 2 + hl;                                           \
      _Pragma("unroll")                                                  \
      for (int dt = 0; dt < 4; dt++) {                                   \
        int d = dt * 32 + l31;                                           \
        int off = (d << 7) | ((slot ^ (d & 7)) << 4);                    \
        bf16x8 vf = *(const bf16x8_a*)((lVp) + off);                     \
        oT[dt] = mfma32(vf, (PB)[kvb], oT[dt]);                          \
      }                                                                  \
    }                                                                    \
  } while (0)

  constexpr int NT = SEQ / 64;  // 32
  STAGE(0, 0);
  STAGE(1, 1);
  WAITV(4);  // tile 0 drained (tile 1's 4 may pend)
  BAR();     // cross-wave: tile 0 visible

  f32x16 scA[2], scB[2];
  bf16x8 pb[4];
  QKT(scA, ldsK);  // tile 0, buf 0

  for (int it = 0; it < NT / 2; ++it) {
    const int t0 = 2 * it;
    {
      const int t = t0;
      BAR();  // all waves' tile-(t-1) reads consumed -> safe to overwrite its buf
      if (t + 2 < NT) STAGE((t + 2) % 3, t + 2);
      SOFTMAX(scA, pb);
      if (t + 2 < NT) { WAITV(4); } else { WAITV(0); }  // drain tile t+1
      BAR();  // cross-wave: tile t+1 staged & visible
      __builtin_amdgcn_s_setprio(1);
      if (t + 1 < NT) QKT(scB, ldsK + ((t + 1) % 3) * 16384);
      PVACC(pb, ldsV + (t % 3) * 16384);
      __builtin_amdgcn_s_setprio(0);
    }
    {
      const int t = t0 + 1;
      BAR();
      if (t + 2 < NT) STAGE((t + 2) % 3, t + 2);
      SOFTMAX(scB, pb);
      if (t + 2 < NT) { WAITV(4); } else { WAITV(0); }
      BAR();
      __builtin_amdgcn_s_setprio(1);
      if (t + 1 < NT) QKT(scA, ldsK + ((t + 1) % 3) * 16384);
      PVACC(pb, ldsV + (t % 3) * 16384);
      __builtin_amdgcn_s_setprio(0);
    }
  }
#undef QKT
#undef SOFTMAX
#undef PVACC

  float lsum = ls2[0] + ls2[1];
  float lsf = lsum + __shfl_xor(lsum, 32);
  float inv = 1.0f / lsf;
  bf16* ob = O + (size_t)qrow * (NHEAD * HD) + h * HD;
#pragma unroll
  for (int dt = 0; dt < 4; dt++)
#pragma unroll
    for (int g = 0; g < 4; g++) {
      u32x2 pr;
      pr[0] = pkbf16(oT[dt][4 * g] * inv, oT[dt][4 * g + 1] * inv);
      pr[1] = pkbf16(oT[dt][4 * g + 2] * inv, oT[dt][4 * g + 3] * inv);
      *(u32x2_a*)(ob + dt * 32 + 8 * g + 4 * hl) = pr;
    }
}

extern "C" void kernel_launch(void* const* d_in, const int* in_sizes, int n_in,
                              void* d_out, int out_size, void* d_ws, size_t ws_size,
                              hipStream_t stream) {
  const float* X  = (const float*)d_in[0];
  const float* Wq = (const float*)d_in[1];
  const float* Wk = (const float*)d_in[2];
  const float* Wv = (const float*)d_in[3];
  const float* Wo = (const float*)d_in[4];
  float* out = (float*)d_out;

  char* ws = (char*)d_ws;
  size_t off = 0;
  auto alloc = [&](size_t bytes) {
    void* p = ws + off;
    off += (bytes + 255) & ~(size_t)255;
    return p;
  };
  bf16* Xb  = (bf16*)alloc((size_t)MROWS * HID * 2);
  // WqT/WkT/WvT adjacent & contiguous -> fused BT [4096][2048]
  bf16* WqT = (bf16*)alloc((size_t)2048 * 2048 * 2);
  bf16* WkT = (bf16*)alloc((size_t)1024 * 2048 * 2);
  bf16* WvT = (bf16*)alloc((size_t)1024 * 2048 * 2);
  bf16* WoT = (bf16*)alloc((size_t)2048 * 2048 * 2);
  bf16* Qb  = (bf16*)alloc((size_t)MROWS * 2048 * 2);
  bf16* Kb  = (bf16*)alloc((size_t)MROWS * 1024 * 2);
  bf16* Vb  = (bf16*)alloc((size_t)MROWS * 1024 * 2);
  bf16* VTb = (bf16*)alloc((size_t)16 * 128 * 2048 * 2);
  bf16* AOb = (bf16*)alloc((size_t)MROWS * 2048 * 2);
  float* ct = (float*)alloc((size_t)SEQ * 64 * 4);
  float* st = (float*)alloc((size_t)SEQ * 64 * 4);

  prep<<<dim3(32, 32, 6), 256, 0, stream>>>(X, Wq, Wk, Wv, Wo, Xb, WqT, WkT, WvT, WoT, ct, st);
  gemmA<<<dim3(32, 32), 256, 0, stream>>>(Xb, WqT, Qb, Kb, Vb, 2048, ct, st);
  vtrans<<<dim3(32, 2, 16), 256, 0, stream>>>(Vb, VTb);
  attn10<<<dim3(8, 16, 2), 512, 0, stream>>>(Qb, Kb, VTb, AOb);
  gemm2p<<<dim3(16, 16), 512, 0, stream>>>(AOb, WoT, out, MROWS, 2048, 2048);

  (void)in_sizes; (void)n_in; (void)out_size; (void)ws_size;
}

// Round 17
// 250.118 us; speedup vs baseline: 1.0537x; 1.0537x over previous
//
#include <hip/hip_runtime.h>
#include <math.h>

typedef __bf16 bf16;
typedef __bf16 bf16x8 __attribute__((ext_vector_type(8)));
typedef __bf16 bf16x4 __attribute__((ext_vector_type(4)));
typedef float f32x2 __attribute__((ext_vector_type(2)));
typedef float f32x4 __attribute__((ext_vector_type(4)));
typedef float f32x16 __attribute__((ext_vector_type(16)));
typedef unsigned int uint;
typedef uint u32x4 __attribute__((ext_vector_type(4)));
typedef uint u32x2 __attribute__((ext_vector_type(2)));
typedef __bf16 bf16x8_a __attribute__((ext_vector_type(8), __may_alias__));
typedef uint u32x2_a __attribute__((ext_vector_type(2), __may_alias__));
typedef __bf16 bf16x4_a __attribute__((ext_vector_type(4), __may_alias__));
typedef __bf16 bf16_a __attribute__((__may_alias__));

constexpr int BATCH = 2;
constexpr int SEQ   = 2048;
constexpr int HID   = 2048;
constexpr int NHEAD = 16;
constexpr int NKV   = 8;
constexpr int HD    = 128;
constexpr int MROWS = BATCH * SEQ; // 4096

#define DEVINL __device__ __forceinline__

// raw barrier with compiler reorder fence (no implicit vmcnt/lgkm drain)
#define BAR()                                 \
  do {                                        \
    asm volatile("" ::: "memory");            \
    __builtin_amdgcn_s_barrier();             \
    asm volatile("" ::: "memory");            \
  } while (0)

#define WAITV(N) asm volatile("s_waitcnt vmcnt(" #N ")" ::: "memory")

DEVINL void async16(void* l, const void* g) {
  __builtin_amdgcn_global_load_lds((const __attribute__((address_space(1))) void*)g,
                                   (__attribute__((address_space(3))) void*)l, 16, 0, 0);
}

DEVINL f32x4 mfma16(bf16x8 a, bf16x8 b, f32x4 c) {
  return __builtin_amdgcn_mfma_f32_16x16x32_bf16(a, b, c, 0, 0, 0);
}
DEVINL f32x16 mfma32(bf16x8 a, bf16x8 b, f32x16 c) {
  return __builtin_amdgcn_mfma_f32_32x32x16_bf16(a, b, c, 0, 0, 0);
}

DEVINL f32x4 fzero4() { f32x4 z; z[0] = 0.f; z[1] = 0.f; z[2] = 0.f; z[3] = 0.f; return z; }

DEVINL float ex2(float x) {
#if __has_builtin(__builtin_amdgcn_exp2f)
  return __builtin_amdgcn_exp2f(x);
#else
  return __expf(x * 0.6931471805599453f);
#endif
}

DEVINL uint pkbf16(float lo, float hi) {
  unsigned short l = __builtin_bit_cast(unsigned short, (bf16)lo);
  unsigned short h = __builtin_bit_cast(unsigned short, (bf16)hi);
  return (uint)l | ((uint)h << 16);
}

// hardware half-wave swap: returns {.x = {a.lo, b.lo}, .y = {a.hi, b.hi}}
DEVINL u32x2 pswap(uint a, uint b) {
#if __has_builtin(__builtin_amdgcn_permlane32_swap)
  return __builtin_amdgcn_permlane32_swap(a, b, false, false);
#else
  int hl = (int)((threadIdx.x >> 5) & 1);
  uint as = __shfl_xor(a, 32), bs = __shfl_xor(b, 32);
  u32x2 r;
  r[0] = hl ? bs : a;  // {a.lo, b.lo}
  r[1] = hl ? b : as;  // {a.hi, b.hi}
  return r;
#endif
}

// ---------------- fused prep: W transposes (z=0..3), rope tables (z=4), X cast (z=5) ----
__global__ __launch_bounds__(256) void prep(const float* __restrict__ X,
                                            const float* __restrict__ Wq,
                                            const float* __restrict__ Wk,
                                            const float* __restrict__ Wv,
                                            const float* __restrict__ Wo,
                                            bf16* __restrict__ Xb,
                                            bf16* __restrict__ WqT, bf16* __restrict__ WkT,
                                            bf16* __restrict__ WvT, bf16* __restrict__ WoT,
                                            float* __restrict__ ct, float* __restrict__ st) {
  const int tid = threadIdx.x;
  const int z = blockIdx.z;
  if (z == 4) {
    int idx = (blockIdx.y * 32 + blockIdx.x) * 256 + tid;
    if (idx < SEQ * 64) {
      int s = idx >> 6, d = idx & 63;
      float freq = powf(10000.0f, -(float)d * (1.0f / 64.0f));
      float a = (float)s * freq;
      ct[idx] = cosf(a);
      st[idx] = sinf(a);
    }
    return;
  }
  if (z == 5) {
    int j = (blockIdx.y * 32 + blockIdx.x) * 256 + tid;
#pragma unroll
    for (int it = 0; it < 8; it++) {
      int e = (it * 262144 + j) * 4;
      float4 v = *(const float4*)(X + e);
      bf16x4 o;
      o[0] = (bf16)v.x; o[1] = (bf16)v.y; o[2] = (bf16)v.z; o[3] = (bf16)v.w;
      *(bf16x4*)(Xb + e) = o;
    }
    return;
  }
  __shared__ bf16 t[64][65];
  const float* W; bf16* WT; int N;
  switch (z) {
    case 0: W = Wq; WT = WqT; N = 2048; break;
    case 1: W = Wk; WT = WkT; N = 1024; break;
    case 2: W = Wv; WT = WvT; N = 1024; break;
    default: W = Wo; WT = WoT; N = 2048; break;
  }
  int n0 = blockIdx.x * 64, k0 = blockIdx.y * 64;
  if (n0 >= N) return;
#pragma unroll
  for (int p = 0; p < 4; p++) {
    int r = (tid >> 4) + p * 16;
    int c4 = (tid & 15) * 4;
    float4 v = *(const float4*)(&W[(size_t)(k0 + r) * N + n0 + c4]);
    t[r][c4 + 0] = (bf16)v.x;
    t[r][c4 + 1] = (bf16)v.y;
    t[r][c4 + 2] = (bf16)v.z;
    t[r][c4 + 3] = (bf16)v.w;
  }
  __syncthreads();
#pragma unroll
  for (int p = 0; p < 4; p++) {
    int nr = (tid >> 4) + p * 16;
    int kb = (tid & 15) * 4;
    bf16x4 o;
    o[0] = t[kb + 0][nr];
    o[1] = t[kb + 1][nr];
    o[2] = t[kb + 2][nr];
    o[3] = t[kb + 3][nr];
    *(bf16x4_a*)(&WT[(size_t)(n0 + nr) * 2048 + k0 + kb]) = o;
  }
}

// ---------------- V[b*S+s][kvh*128+d] -> VT[(b*8+kvh)*128+d][s] ----------------
__global__ __launch_bounds__(256) void vtrans(const bf16* __restrict__ V, bf16* __restrict__ VT) {
  __shared__ bf16 t[64][65];
  int s0 = blockIdx.x * 64, d0 = blockIdx.y * 64;
  int bh = blockIdx.z, b = bh >> 3, kvh = bh & 7;
  for (int i = threadIdx.x; i < 4096; i += 256) {
    int r = i >> 6, c = i & 63;
    t[r][c] = V[(size_t)(b * SEQ + s0 + r) * (NKV * HD) + kvh * HD + d0 + c];
  }
  __syncthreads();
  for (int i = threadIdx.x; i < 4096; i += 256) {
    int r = i >> 6, c = i & 63;
    VT[((size_t)bh * HD + d0 + r) * SEQ + s0 + c] = t[c][r];
  }
}

// ======== 256x128-tile fused QKV GEMM, gemm2p structure (1 phase/K-step, 32 MFMA) ========
// 512 thr / 8 waves (4M x 2N-interleave); wave = 64 rows x 64 cols (16-col interleave).
// A: 2 bufs (in-place t+2 staging); B: 3 bufs. Stage B(t+2)+A(t+2) after reads-BAR;
// steady-state WAITV(6) is pass-through (tile t+1's loads issued a full K-step earlier).
// Epilogue: RoPE for cols<3072 (pair acc[mt][nt^2]); Q pre-scale cols<2048; Q/K/V split.
__global__ __launch_bounds__(512, 2) void gemmB(const bf16* __restrict__ A,
                                                const bf16* __restrict__ BT,
                                                bf16* __restrict__ C0, bf16* __restrict__ C1,
                                                bf16* __restrict__ C2, int K,
                                                const float* __restrict__ ct,
                                                const float* __restrict__ st) {
  __shared__ alignas(16) char ldsA[65536];  // [buf:2][half:2][128r][64k]
  __shared__ alignas(16) char ldsB[49152];  // [buf:3][128c][64k]
  const int tid = threadIdx.x, lane = tid & 63, w = tid >> 6;
  const int l15 = lane & 15, l4 = lane >> 4;
  const int wm = w >> 1, wn = w & 1;
  const int gx = 32;                 // N=4096 / 128
  const int nwg = gx * gridDim.y;    // 512
  int id = blockIdx.y * gx + blockIdx.x;
  id = (id & 7) * (nwg >> 3) + (id >> 3);
  const int row0 = (id / gx) * 256;
  const int col0 = (id % gx) * 128;

  f32x4 acc[4][4];
#pragma unroll
  for (int mt = 0; mt < 4; mt++)
#pragma unroll
    for (int nt = 0; nt < 4; nt++) acc[mt][nt] = fzero4();

  const int rG0 = tid >> 3, sG0 = ((tid & 7) ^ (rG0 & 7)) * 8;
  const int ci1 = 512 + tid;
  const int rG1 = ci1 >> 3, sG1 = ((ci1 & 7) ^ (rG1 & 7)) * 8;
  const int dst0 = tid * 16, dst1 = (512 + tid) * 16;

  const bf16* Asrc = A + (size_t)row0 * K;
  const bf16* Bsrc = BT + (size_t)col0 * K;
  const int nk = K >> 6;

#define STG_A2(half, kt, buf)                                        \
  {                                                                  \
    char* d = ldsA + (buf) * 32768 + (half) * 16384;                 \
    const bf16* s = Asrc + (size_t)((half) * 128) * K + (kt) * 64;   \
    async16(d + dst0, s + (size_t)rG0 * K + sG0);                    \
    async16(d + dst1, s + (size_t)rG1 * K + sG1);                    \
  }
#define STG_B2(kt, buf)                                              \
  {                                                                  \
    char* d = ldsB + (buf) * 16384;                                  \
    const bf16* s = Bsrc + (kt) * 64;                                \
    async16(d + dst0, s + (size_t)rG0 * K + sG0);                    \
    async16(d + dst1, s + (size_t)rG1 * K + sG1);                    \
  }

  STG_B2(0, 0) STG_A2(0, 0, 0) STG_A2(1, 0, 0)
  STG_B2(1, 1) STG_A2(0, 1, 1) STG_A2(1, 1, 1)
  WAITV(6);
  BAR();

  bf16x8 af[8];
  bf16x8 bfr[8];

  for (int t = 0; t < nk; ++t) {
    const int abuf = t & 1;
    int bb = t % 3;
    const char* bA = ldsA + abuf * 32768 + (wm >> 1) * 16384;
    const char* bB = ldsB + bb * 16384;
    const bool s2 = (t + 2) < nk;
    int bb2 = bb + 2; if (bb2 >= 3) bb2 -= 3;

    // reads: A frags (8) + B all nt (8)
#pragma unroll
    for (int mt = 0; mt < 4; mt++)
#pragma unroll
      for (int kc = 0; kc < 2; kc++) {
        int r = (wm & 1) * 64 + mt * 16 + l15;
        int off = ((r << 7) + ((kc * 4 + l4) << 4)) ^ ((r & 7) << 4);
        af[mt * 2 + kc] = *(const bf16x8_a*)(bA + off);
      }
#pragma unroll
    for (int nt = 0; nt < 4; nt++)
#pragma unroll
      for (int kc = 0; kc < 2; kc++) {
        int c = wn * 16 + nt * 32 + l15;
        int off = ((c << 7) + ((kc * 4 + l4) << 4)) ^ ((c & 7) << 4);
        bfr[nt * 2 + kc] = *(const bf16x8_a*)(bB + off);
      }
    BAR();  // all waves' reads done -> safe to stage into abuf / bb2
    if (s2) { STG_B2(t + 2, bb2) STG_A2(0, t + 2, abuf) STG_A2(1, t + 2, abuf) }
    __builtin_amdgcn_s_setprio(1);
#pragma unroll
    for (int mt = 0; mt < 4; mt++)
#pragma unroll
      for (int nt = 0; nt < 4; nt++)
#pragma unroll
        for (int kc = 0; kc < 2; kc++)
          acc[mt][nt] = mfma16(af[mt * 2 + kc], bfr[nt * 2 + kc], acc[mt][nt]);
    __builtin_amdgcn_s_setprio(0);
    if (s2) { WAITV(6); } else { WAITV(0); }
    BAR();
  }
#undef STG_A2
#undef STG_B2

  // ---- epilogue: RoPE + split store; pair col^64 = acc[mt][nt^2] ----
#pragma unroll
  for (int mt = 0; mt < 4; mt++)
#pragma unroll
    for (int nt = 0; nt < 4; nt++)
#pragma unroll
      for (int rg = 0; rg < 4; rg++) {
        int row = row0 + wm * 64 + mt * 16 + l4 * 4 + rg;
        int cl = col0 + wn * 16 + nt * 32 + l15;
        float v = acc[mt][nt][rg];
        if (cl < 3072) {  // RoPE for Q and K ranges (cl&63 = wn*16+(nt&1)*32+l15)
          int s = row & (SEQ - 1);
          float pv = acc[mt][nt ^ 2][rg];
          float cc = ct[s * 64 + (cl & 63)];
          float ss = st[s * 64 + (cl & 63)];
          v = (nt < 2) ? fmaf(v, cc, -pv * ss) : fmaf(v, cc, pv * ss);
        }
        if (cl < 2048) {
          v *= 1.7677669529663689e-3f;  // pre-scale Q by 1/(50*sqrt(128))
          C0[(size_t)row * 2048 + cl] = (bf16)v;
        } else if (cl < 3072) {
          C1[(size_t)row * 1024 + (cl - 2048)] = (bf16)v;
        } else {
          C2[(size_t)row * 1024 + (cl - 3072)] = (bf16)v;
        }
      }
}

// ================= 256x128 GEMM (Wo) — merged 1-phase/tile (unchanged from R15) =========
__global__ __launch_bounds__(512, 2) void gemm2p(const bf16* __restrict__ A,
                                                 const bf16* __restrict__ BT,
                                                 float* __restrict__ C, int M, int N, int K) {
  __shared__ alignas(16) char ldsA[65536];  // [buf:2][half:2][128r][64k]
  __shared__ alignas(16) char ldsB[49152];  // [buf:3][128c][64k]
  const int tid = threadIdx.x, lane = tid & 63, w = tid >> 6;
  const int l15 = lane & 15, l4 = lane >> 4;
  const int wm = w >> 1, wn = w & 1;
  const int gx = gridDim.x;
  const int nwg = gx * gridDim.y;
  int id = blockIdx.y * gx + blockIdx.x;
  id = (id & 7) * (nwg >> 3) + (id >> 3);
  const int row0 = (id / gx) * 256;
  const int col0 = (id % gx) * 128;

  f32x4 acc[4][4];
#pragma unroll
  for (int mt = 0; mt < 4; mt++)
#pragma unroll
    for (int nt = 0; nt < 4; nt++) acc[mt][nt] = fzero4();

  const int rG0 = tid >> 3, sG0 = ((tid & 7) ^ (rG0 & 7)) * 8;
  const int ci1 = 512 + tid;
  const int rG1 = ci1 >> 3, sG1 = ((ci1 & 7) ^ (rG1 & 7)) * 8;
  const int dst0 = tid * 16, dst1 = (512 + tid) * 16;

  const bf16* Asrc = A + (size_t)row0 * K;
  const bf16* Bsrc = BT + (size_t)col0 * K;
  const int nk = K >> 6;

#define STG_A2(half, kt, buf)                                        \
  {                                                                  \
    char* d = ldsA + (buf) * 32768 + (half) * 16384;                 \
    const bf16* s = Asrc + (size_t)((half) * 128) * K + (kt) * 64;   \
    async16(d + dst0, s + (size_t)rG0 * K + sG0);                    \
    async16(d + dst1, s + (size_t)rG1 * K + sG1);                    \
  }
#define STG_B2(kt, buf)                                              \
  {                                                                  \
    char* d = ldsB + (buf) * 16384;                                  \
    const bf16* s = Bsrc + (kt) * 64;                                \
    async16(d + dst0, s + (size_t)rG0 * K + sG0);                    \
    async16(d + dst1, s + (size_t)rG1 * K + sG1);                    \
  }

  STG_B2(0, 0) STG_A2(0, 0, 0) STG_A2(1, 0, 0)
  STG_B2(1, 1) STG_A2(0, 1, 1) STG_A2(1, 1, 1)
  WAITV(6);
  BAR();

  bf16x8 af[8];
  bf16x8 bfr[8];

  for (int t = 0; t < nk; ++t) {
    const int abuf = t & 1;
    int bb = t % 3;
    const char* bA = ldsA + abuf * 32768 + (wm >> 1) * 16384;
    const char* bB = ldsB + bb * 16384;
    const bool s2 = (t + 2) < nk;
    int bb2 = bb + 2; if (bb2 >= 3) bb2 -= 3;

#pragma unroll
    for (int mt = 0; mt < 4; mt++)
#pragma unroll
      for (int kc = 0; kc < 2; kc++) {
        int r = (wm & 1) * 64 + mt * 16 + l15;
        int off = ((r << 7) + ((kc * 4 + l4) << 4)) ^ ((r & 7) << 4);
        af[mt * 2 + kc] = *(const bf16x8_a*)(bA + off);
      }
#pragma unroll
    for (int nt = 0; nt < 4; nt++)
#pragma unroll
      for (int kc = 0; kc < 2; kc++) {
        int c = wn * 16 + nt * 32 + l15;
        int off = ((c << 7) + ((kc * 4 + l4) << 4)) ^ ((c & 7) << 4);
        bfr[nt * 2 + kc] = *(const bf16x8_a*)(bB + off);
      }
    BAR();  // all waves' reads done -> safe to stage into abuf
    if (s2) { STG_B2(t + 2, bb2) STG_A2(0, t + 2, abuf) STG_A2(1, t + 2, abuf) }
    __builtin_amdgcn_s_setprio(1);
#pragma unroll
    for (int mt = 0; mt < 4; mt++)
#pragma unroll
      for (int nt = 0; nt < 4; nt++)
#pragma unroll
        for (int kc = 0; kc < 2; kc++)
          acc[mt][nt] = mfma16(af[mt * 2 + kc], bfr[nt * 2 + kc], acc[mt][nt]);
    __builtin_amdgcn_s_setprio(0);
    if (s2) { WAITV(6); } else { WAITV(0); }
    BAR();
  }
#undef STG_A2
#undef STG_B2

#pragma unroll
  for (int mt = 0; mt < 4; mt++)
#pragma unroll
    for (int nt = 0; nt < 4; nt++)
#pragma unroll
      for (int rg = 0; rg < 4; rg++) {
        int row = row0 + wm * 64 + mt * 16 + l4 * 4 + rg;
        int cl = col0 + wn * 16 + nt * 32 + l15;
        C[(size_t)row * N + cl] = acc[mt][nt][rg];
      }
}

// ========== Flash attention v10 (unchanged from R14, race-free) ==========
__global__ __launch_bounds__(512, 2) void attn10(const bf16* __restrict__ Q,
                                                 const bf16* __restrict__ Kg,
                                                 const bf16* __restrict__ VTg,
                                                 bf16* __restrict__ O) {
  __shared__ alignas(16) char ldsK[49152];   // 3 x [64 kv][128 d], 16-slot swizzle
  __shared__ alignas(16) char ldsV[49152];   // 3 x [128 d][64 kv], 8-slot swizzle
  const int tid = threadIdx.x, lane = tid & 63, w = tid >> 6;
  const int l31 = lane & 31, hl = lane >> 5;

  const int nx = gridDim.x, ny = gridDim.y;
  const int nwg = nx * ny * gridDim.z;  // 256
  int id = (blockIdx.z * ny + blockIdx.y) * nx + blockIdx.x;
  id = (id & 7) * (nwg >> 3) + (id >> 3);
  const int qt = id % nx; id /= nx;
  const int h = id % ny; const int b = id / ny;
  const int kvh = h >> 1;
  const int qrow = b * SEQ + qt * 256 + w * 32 + l31;

  bf16x8 qf[8];
  const bf16* qp = Q + (size_t)qrow * (NHEAD * HD) + h * HD + hl * 8;
#pragma unroll
  for (int kc = 0; kc < 8; kc++) qf[kc] = *(const bf16x8_a*)(qp + kc * 16);

  f32x16 oT[4];
#pragma unroll
  for (int dt = 0; dt < 4; dt++)
#pragma unroll
    for (int r = 0; r < 16; r++) oT[dt][r] = 0.f;
  f32x2 ls2; ls2[0] = 0.f; ls2[1] = 0.f;

  const int rK = tid >> 4, sK = (tid & 15) ^ (rK & 15);  // 16-slot swizzle
  const int rV = tid >> 3, sV = (tid & 7) ^ (rV & 7);    // 8-slot swizzle
  const size_t koff0 = (size_t)(b * SEQ + rK) * (NKV * HD) + kvh * HD + sK * 8;
  const size_t voff0 = ((size_t)(b * NKV + kvh) * HD + rV) * SEQ + sV * 8;

  const float Ac = 72.13475204444817f;    // 50*log2(e)
  const float Bc = -24.044917348149389f;  // Ac * (-1/3)

  auto STAGE = [&](int buf, int t) {
    char* dK = ldsK + buf * 16384;
    char* dV = ldsV + buf * 16384;
    const bf16* ks = Kg + koff0 + (size_t)t * (64 * NKV * HD);
    const bf16* vs = VTg + voff0 + (size_t)t * 64;
    async16(dK + tid * 16, ks);
    async16(dK + (512 + tid) * 16, ks + (size_t)32 * (NKV * HD));
    async16(dV + tid * 16, vs);
    async16(dV + (512 + tid) * 16, vs + (size_t)64 * SEQ);
  };

  const int kvr0 = l31, kvr1 = 32 + l31;

#define QKT(SC, lKp)                                                     \
  do {                                                                   \
    _Pragma("unroll")                                                    \
    for (int r = 0; r < 16; r++) { (SC)[0][r] = 0.f; (SC)[1][r] = 0.f; } \
    _Pragma("unroll")                                                    \
    for (int kc = 0; kc < 8; kc++) {                                     \
      int slot = kc * 2 + hl;                                            \
      int off0 = (kvr0 << 8) | ((slot ^ (kvr0 & 15)) << 4);              \
      int off1 = (kvr1 << 8) | ((slot ^ (kvr1 & 15)) << 4);              \
      bf16x8 kf0 = *(const bf16x8_a*)((lKp) + off0);                     \
      bf16x8 kf1 = *(const bf16x8_a*)((lKp) + off1);                     \
      (SC)[0] = mfma32(kf0, qf[kc], (SC)[0]);                            \
      (SC)[1] = mfma32(kf1, qf[kc], (SC)[1]);                            \
    }                                                                    \
  } while (0)

#define SOFTMAX(SC, PB)                                                  \
  do {                                                                   \
    _Pragma("unroll")                                                    \
    for (int ntb = 0; ntb < 2; ntb++) {                                  \
      uint u[4][2];                                                      \
      _Pragma("unroll")                                                  \
      for (int r2 = 0; r2 < 8; r2++) {                                   \
        f32x2 z; z[0] = (SC)[ntb][2 * r2]; z[1] = (SC)[ntb][2 * r2 + 1]; \
        f32x2 z2 = z * z;                                                \
        f32x2 wv = z2 * Bc + Ac;                                         \
        f32x2 e = z * wv;                                                \
        float p0 = ex2(e[0]), p1 = ex2(e[1]);                            \
        ls2[0] += p0; ls2[1] += p1;                                      \
        u[r2 >> 1][r2 & 1] = pkbf16(p0, p1);                             \
      }                                                                  \
      _Pragma("unroll")                                                  \
      for (int sub = 0; sub < 2; sub++) {                                \
        u32x2 r0 = pswap(u[2 * sub][0], u[2 * sub + 1][0]);              \
        u32x2 r1 = pswap(u[2 * sub][1], u[2 * sub + 1][1]);              \
        u32x4 bu;                                                        \
        bu[0] = r0[0];                                                   \
        bu[1] = r1[0];                                                   \
        bu[2] = r0[1];                                                   \
        bu[3] = r1[1];                                                   \
        (PB)[ntb * 2 + sub] = __builtin_bit_cast(bf16x8, bu);            \
      }                                                                  \
    }                                                                    \
  } while (0)

#define PVACC(PB, lVp)                                                   \
  do {                                                                   \
    _Pragma("unroll")                                                    \
    for (int kvb = 0; kvb < 4; kvb++) {                                  \
      int slot = kvb * 2 + hl;                                           \
      _Pragma("unroll")                                                  \
      for (int dt = 0; dt < 4; dt++) {                                   \
        int d = dt * 32 + l31;                                           \
        int off = (d << 7) | ((slot ^ (d & 7)) << 4);                    \
        bf16x8 vf = *(const bf16x8_a*)((lVp) + off);                     \
        oT[dt] = mfma32(vf, (PB)[kvb], oT[dt]);                          \
      }                                                                  \
    }                                                                    \
  } while (0)

  constexpr int NT = SEQ / 64;  // 32
  STAGE(0, 0);
  STAGE(1, 1);
  WAITV(4);  // tile 0 drained (tile 1's 4 may pend)
  BAR();     // cross-wave: tile 0 visible

  f32x16 scA[2], scB[2];
  bf16x8 pb[4];
  QKT(scA, ldsK);  // tile 0, buf 0

  for (int it = 0; it < NT / 2; ++it) {
    const int t0 = 2 * it;
    {
      const int t = t0;
      BAR();  // all waves' tile-(t-1) reads consumed -> safe to overwrite its buf
      if (t + 2 < NT) STAGE((t + 2) % 3, t + 2);
      SOFTMAX(scA, pb);
      if (t + 2 < NT) { WAITV(4); } else { WAITV(0); }  // drain tile t+1
      BAR();  // cross-wave: tile t+1 staged & visible
      __builtin_amdgcn_s_setprio(1);
      if (t + 1 < NT) QKT(scB, ldsK + ((t + 1) % 3) * 16384);
      PVACC(pb, ldsV + (t % 3) * 16384);
      __builtin_amdgcn_s_setprio(0);
    }
    {
      const int t = t0 + 1;
      BAR();
      if (t + 2 < NT) STAGE((t + 2) % 3, t + 2);
      SOFTMAX(scB, pb);
      if (t + 2 < NT) { WAITV(4); } else { WAITV(0); }
      BAR();
      __builtin_amdgcn_s_setprio(1);
      if (t + 1 < NT) QKT(scA, ldsK + ((t + 1) % 3) * 16384);
      PVACC(pb, ldsV + (t % 3) * 16384);
      __builtin_amdgcn_s_setprio(0);
    }
  }
#undef QKT
#undef SOFTMAX
#undef PVACC

  float lsum = ls2[0] + ls2[1];
  float lsf = lsum + __shfl_xor(lsum, 32);
  float inv = 1.0f / lsf;
  bf16* ob = O + (size_t)qrow * (NHEAD * HD) + h * HD;
#pragma unroll
  for (int dt = 0; dt < 4; dt++)
#pragma unroll
    for (int g = 0; g < 4; g++) {
      u32x2 pr;
      pr[0] = pkbf16(oT[dt][4 * g] * inv, oT[dt][4 * g + 1] * inv);
      pr[1] = pkbf16(oT[dt][4 * g + 2] * inv, oT[dt][4 * g + 3] * inv);
      *(u32x2_a*)(ob + dt * 32 + 8 * g + 4 * hl) = pr;
    }
}

extern "C" void kernel_launch(void* const* d_in, const int* in_sizes, int n_in,
                              void* d_out, int out_size, void* d_ws, size_t ws_size,
                              hipStream_t stream) {
  const float* X  = (const float*)d_in[0];
  const float* Wq = (const float*)d_in[1];
  const float* Wk = (const float*)d_in[2];
  const float* Wv = (const float*)d_in[3];
  const float* Wo = (const float*)d_in[4];
  float* out = (float*)d_out;

  char* ws = (char*)d_ws;
  size_t off = 0;
  auto alloc = [&](size_t bytes) {
    void* p = ws + off;
    off += (bytes + 255) & ~(size_t)255;
    return p;
  };
  bf16* Xb  = (bf16*)alloc((size_t)MROWS * HID * 2);
  // WqT/WkT/WvT adjacent & contiguous -> fused BT [4096][2048]
  bf16* WqT = (bf16*)alloc((size_t)2048 * 2048 * 2);
  bf16* WkT = (bf16*)alloc((size_t)1024 * 2048 * 2);
  bf16* WvT = (bf16*)alloc((size_t)1024 * 2048 * 2);
  bf16* WoT = (bf16*)alloc((size_t)2048 * 2048 * 2);
  bf16* Qb  = (bf16*)alloc((size_t)MROWS * 2048 * 2);
  bf16* Kb  = (bf16*)alloc((size_t)MROWS * 1024 * 2);
  bf16* Vb  = (bf16*)alloc((size_t)MROWS * 1024 * 2);
  bf16* VTb = (bf16*)alloc((size_t)16 * 128 * 2048 * 2);
  bf16* AOb = (bf16*)alloc((size_t)MROWS * 2048 * 2);
  float* ct = (float*)alloc((size_t)SEQ * 64 * 4);
  float* st = (float*)alloc((size_t)SEQ * 64 * 4);

  prep<<<dim3(32, 32, 6), 256, 0, stream>>>(X, Wq, Wk, Wv, Wo, Xb, WqT, WkT, WvT, WoT, ct, st);
  gemmB<<<dim3(32, 16), 512, 0, stream>>>(Xb, WqT, Qb, Kb, Vb, 2048, ct, st);
  vtrans<<<dim3(32, 2, 16), 256, 0, stream>>>(Vb, VTb);
  attn10<<<dim3(8, 16, 2), 512, 0, stream>>>(Qb, Kb, VTb, AOb);
  gemm2p<<<dim3(16, 16), 512, 0, stream>>>(AOb, WoT, out, MROWS, 2048, 2048);

  (void)in_sizes; (void)n_in; (void)out_size; (void)ws_size;
}

// Round 18
// 227.946 us; speedup vs baseline: 1.1562x; 1.0973x over previous
//
#include <hip/hip_runtime.h>
#include <math.h>

typedef __bf16 bf16;
typedef __bf16 bf16x8 __attribute__((ext_vector_type(8)));
typedef __bf16 bf16x4 __attribute__((ext_vector_type(4)));
typedef float f32x2 __attribute__((ext_vector_type(2)));
typedef float f32x4 __attribute__((ext_vector_type(4)));
typedef float f32x16 __attribute__((ext_vector_type(16)));
typedef unsigned int uint;
typedef uint u32x4 __attribute__((ext_vector_type(4)));
typedef uint u32x2 __attribute__((ext_vector_type(2)));
typedef __bf16 bf16x8_a __attribute__((ext_vector_type(8), __may_alias__));
typedef uint u32x2_a __attribute__((ext_vector_type(2), __may_alias__));
typedef __bf16 bf16x4_a __attribute__((ext_vector_type(4), __may_alias__));
typedef __bf16 bf16_a __attribute__((__may_alias__));

constexpr int BATCH = 2;
constexpr int SEQ   = 2048;
constexpr int HID   = 2048;
constexpr int NHEAD = 16;
constexpr int NKV   = 8;
constexpr int HD    = 128;
constexpr int MROWS = BATCH * SEQ; // 4096

#define DEVINL __device__ __forceinline__

// raw barrier with compiler reorder fence (no implicit vmcnt/lgkm drain)
#define BAR()                                 \
  do {                                        \
    asm volatile("" ::: "memory");            \
    __builtin_amdgcn_s_barrier();             \
    asm volatile("" ::: "memory");            \
  } while (0)

#define WAITV(N) asm volatile("s_waitcnt vmcnt(" #N ")" ::: "memory")

DEVINL void async16(void* l, const void* g) {
  __builtin_amdgcn_global_load_lds((const __attribute__((address_space(1))) void*)g,
                                   (__attribute__((address_space(3))) void*)l, 16, 0, 0);
}

DEVINL f32x4 mfma16(bf16x8 a, bf16x8 b, f32x4 c) {
  return __builtin_amdgcn_mfma_f32_16x16x32_bf16(a, b, c, 0, 0, 0);
}
DEVINL f32x16 mfma32(bf16x8 a, bf16x8 b, f32x16 c) {
  return __builtin_amdgcn_mfma_f32_32x32x16_bf16(a, b, c, 0, 0, 0);
}

DEVINL f32x4 fzero4() { f32x4 z; z[0] = 0.f; z[1] = 0.f; z[2] = 0.f; z[3] = 0.f; return z; }

DEVINL float ex2(float x) {
#if __has_builtin(__builtin_amdgcn_exp2f)
  return __builtin_amdgcn_exp2f(x);
#else
  return __expf(x * 0.6931471805599453f);
#endif
}

DEVINL uint pkbf16(float lo, float hi) {
  unsigned short l = __builtin_bit_cast(unsigned short, (bf16)lo);
  unsigned short h = __builtin_bit_cast(unsigned short, (bf16)hi);
  return (uint)l | ((uint)h << 16);
}

// hardware half-wave swap: returns {.x = {a.lo, b.lo}, .y = {a.hi, b.hi}}
DEVINL u32x2 pswap(uint a, uint b) {
#if __has_builtin(__builtin_amdgcn_permlane32_swap)
  return __builtin_amdgcn_permlane32_swap(a, b, false, false);
#else
  int hl = (int)((threadIdx.x >> 5) & 1);
  uint as = __shfl_xor(a, 32), bs = __shfl_xor(b, 32);
  u32x2 r;
  r[0] = hl ? bs : a;  // {a.lo, b.lo}
  r[1] = hl ? b : as;  // {a.hi, b.hi}
  return r;
#endif
}

// ---------------- fused prep: W transposes (z=0..3), rope tables (z=4), X cast (z=5) ----
__global__ __launch_bounds__(256) void prep(const float* __restrict__ X,
                                            const float* __restrict__ Wq,
                                            const float* __restrict__ Wk,
                                            const float* __restrict__ Wv,
                                            const float* __restrict__ Wo,
                                            bf16* __restrict__ Xb,
                                            bf16* __restrict__ WqT, bf16* __restrict__ WkT,
                                            bf16* __restrict__ WvT, bf16* __restrict__ WoT,
                                            float* __restrict__ ct, float* __restrict__ st) {
  const int tid = threadIdx.x;
  const int z = blockIdx.z;
  if (z == 4) {
    int idx = (blockIdx.y * 32 + blockIdx.x) * 256 + tid;
    if (idx < SEQ * 64) {
      int s = idx >> 6, d = idx & 63;
      float freq = powf(10000.0f, -(float)d * (1.0f / 64.0f));
      float a = (float)s * freq;
      ct[idx] = cosf(a);
      st[idx] = sinf(a);
    }
    return;
  }
  if (z == 5) {
    int j = (blockIdx.y * 32 + blockIdx.x) * 256 + tid;
#pragma unroll
    for (int it = 0; it < 8; it++) {
      int e = (it * 262144 + j) * 4;
      float4 v = *(const float4*)(X + e);
      bf16x4 o;
      o[0] = (bf16)v.x; o[1] = (bf16)v.y; o[2] = (bf16)v.z; o[3] = (bf16)v.w;
      *(bf16x4*)(Xb + e) = o;
    }
    return;
  }
  __shared__ bf16 t[64][65];
  const float* W; bf16* WT; int N;
  switch (z) {
    case 0: W = Wq; WT = WqT; N = 2048; break;
    case 1: W = Wk; WT = WkT; N = 1024; break;
    case 2: W = Wv; WT = WvT; N = 1024; break;
    default: W = Wo; WT = WoT; N = 2048; break;
  }
  int n0 = blockIdx.x * 64, k0 = blockIdx.y * 64;
  if (n0 >= N) return;
#pragma unroll
  for (int p = 0; p < 4; p++) {
    int r = (tid >> 4) + p * 16;
    int c4 = (tid & 15) * 4;
    float4 v = *(const float4*)(&W[(size_t)(k0 + r) * N + n0 + c4]);
    t[r][c4 + 0] = (bf16)v.x;
    t[r][c4 + 1] = (bf16)v.y;
    t[r][c4 + 2] = (bf16)v.z;
    t[r][c4 + 3] = (bf16)v.w;
  }
  __syncthreads();
#pragma unroll
  for (int p = 0; p < 4; p++) {
    int nr = (tid >> 4) + p * 16;
    int kb = (tid & 15) * 4;
    bf16x4 o;
    o[0] = t[kb + 0][nr];
    o[1] = t[kb + 1][nr];
    o[2] = t[kb + 2][nr];
    o[3] = t[kb + 3][nr];
    *(bf16x4_a*)(&WT[(size_t)(n0 + nr) * 2048 + k0 + kb]) = o;
  }
}

// ================= 256x256 GEMM — merged 2-phase/tile (from R15, best QKV) =========
// pA: read A-lo(8)+B-h0(4)+B-h1(4); BAR; stage B0,B1(t+2); 32 MFMA; BAR
// pB: read A-hi(8); BAR; stage A0,A1(t+2); 32 MFMA; WAITV(8); BAR
// Epilogue: RoPE cols<3072 (pair acc[mt][nt^1]); Q pre-scale; V written TRANSPOSED
// directly into VT[(b*8+kvh)*128+d][s] (vtrans kernel eliminated).
template <int EPI>
__global__ __launch_bounds__(512, 2) void gemm8p(const bf16* __restrict__ A,
                                                 const bf16* __restrict__ BT,
                                                 void* __restrict__ C0, void* __restrict__ C1,
                                                 void* __restrict__ C2, int M, int N, int K,
                                                 const float* __restrict__ ct,
                                                 const float* __restrict__ st) {
  __shared__ alignas(16) char ldsA[65536];  // [buf][half][128r][64k]
  __shared__ alignas(16) char ldsB[65536];
  const int tid = threadIdx.x, lane = tid & 63, w = tid >> 6;
  const int l15 = lane & 15, l4 = lane >> 4;
  const int wm = w >> 2, wn = w & 3;
  const int gx = gridDim.x;
  const int nwg = gx * gridDim.y;
  int id = blockIdx.y * gx + blockIdx.x;
  id = (id & 7) * (nwg >> 3) + (id >> 3);
  const int row0 = (id / gx) * 256;
  const int col0 = (id % gx) * 256;

  f32x4 acc[8][4];
#pragma unroll
  for (int mt = 0; mt < 8; mt++)
#pragma unroll
    for (int nt = 0; nt < 4; nt++) acc[mt][nt] = fzero4();

  const int rG0 = tid >> 3, sG0 = ((tid & 7) ^ (rG0 & 7)) * 8;
  const int ci1 = 512 + tid;
  const int rG1 = ci1 >> 3, sG1 = ((ci1 & 7) ^ (rG1 & 7)) * 8;
  const int dst0 = tid * 16, dst1 = (512 + tid) * 16;

  const bf16* Asrc = A + (size_t)row0 * K;
  const bf16* Bsrc = BT + (size_t)col0 * K;
  const int nk = K >> 6;

#define STG_A(half, kt, buf)                                         \
  {                                                                  \
    char* d = ldsA + (buf) * 32768 + (half) * 16384;                 \
    const bf16* s = Asrc + (size_t)((half) * 128) * K + (kt) * 64;   \
    async16(d + dst0, s + (size_t)rG0 * K + sG0);                    \
    async16(d + dst1, s + (size_t)rG1 * K + sG1);                    \
  }
#define STG_B(half, kt, buf)                                         \
  {                                                                  \
    char* d = ldsB + (buf) * 32768 + (half) * 16384;                 \
    const bf16* s = Bsrc + (size_t)((half) * 128) * K + (kt) * 64;   \
    async16(d + dst0, s + (size_t)rG0 * K + sG0);                    \
    async16(d + dst1, s + (size_t)rG1 * K + sG1);                    \
  }

  STG_A(0, 0, 0) STG_A(1, 0, 0) STG_B(0, 0, 0) STG_B(1, 0, 0)
  STG_B(0, 1, 1) STG_B(1, 1, 1) STG_A(0, 1, 1) STG_A(1, 1, 1)
  WAITV(8);
  BAR();

  bf16x8 af[8];
  bf16x8 bfr[2][4];

  for (int t = 0; t < nk; ++t) {
    const int buf = t & 1;
    const char* bA = ldsA + buf * 32768 + wm * 16384;
    const char* bB = ldsB + buf * 32768;
    const bool s2 = (t + 2) < nk;

    // ---- pA: read A-lo + B-h0 + B-h1 ----
#pragma unroll
    for (int mtp = 0; mtp < 4; mtp++)
#pragma unroll
      for (int kc = 0; kc < 2; kc++) {
        int r = mtp * 16 + l15;
        int off = ((r << 7) + ((kc * 4 + l4) << 4)) ^ ((r & 7) << 4);
        af[mtp * 2 + kc] = *(const bf16x8_a*)(bA + off);
      }
#pragma unroll
    for (int ntp = 0; ntp < 2; ntp++)
#pragma unroll
      for (int kc = 0; kc < 2; kc++) {
        int c = wn * 16 + ntp * 64 + l15;
        int off = ((c << 7) + ((kc * 4 + l4) << 4)) ^ ((c & 7) << 4);
        bfr[0][ntp * 2 + kc] = *(const bf16x8_a*)(bB + off);
        bfr[1][ntp * 2 + kc] = *(const bf16x8_a*)(bB + 16384 + off);
      }
    BAR();  // all waves' reads of buf complete -> safe to stage into buf
    if (s2) { STG_B(0, t + 2, buf) STG_B(1, t + 2, buf) }
    __builtin_amdgcn_s_setprio(1);
#pragma unroll
    for (int mtp = 0; mtp < 4; mtp++)
#pragma unroll
      for (int half = 0; half < 2; half++)
#pragma unroll
        for (int ntp = 0; ntp < 2; ntp++)
#pragma unroll
          for (int kc = 0; kc < 2; kc++)
            acc[mtp][half * 2 + ntp] =
                mfma16(af[mtp * 2 + kc], bfr[half][ntp * 2 + kc], acc[mtp][half * 2 + ntp]);
    __builtin_amdgcn_s_setprio(0);
    BAR();

    // ---- pB: read A-hi ----
#pragma unroll
    for (int mtp = 0; mtp < 4; mtp++)
#pragma unroll
      for (int kc = 0; kc < 2; kc++) {
        int r = 64 + mtp * 16 + l15;
        int off = ((r << 7) + ((kc * 4 + l4) << 4)) ^ ((r & 7) << 4);
        af[mtp * 2 + kc] = *(const bf16x8_a*)(bA + off);
      }
    BAR();
    if (s2) { STG_A(0, t + 2, buf) STG_A(1, t + 2, buf) }
    __builtin_amdgcn_s_setprio(1);
#pragma unroll
    for (int mtp = 0; mtp < 4; mtp++)
#pragma unroll
      for (int half = 0; half < 2; half++)
#pragma unroll
        for (int ntp = 0; ntp < 2; ntp++)
#pragma unroll
          for (int kc = 0; kc < 2; kc++)
            acc[mtp + 4][half * 2 + ntp] =
                mfma16(af[mtp * 2 + kc], bfr[half][ntp * 2 + kc], acc[mtp + 4][half * 2 + ntp]);
    __builtin_amdgcn_s_setprio(0);
    if (s2) { WAITV(8); } else { WAITV(0); }
    BAR();
  }
#undef STG_A
#undef STG_B

  // ---- epilogue (acc index nt = half*2+ntp -> col = half*128 + ntp*64 + wn*16 + l15) ----
#pragma unroll
  for (int mt = 0; mt < 8; mt++)
#pragma unroll
    for (int nt = 0; nt < 4; nt++)
#pragma unroll
      for (int rg = 0; rg < 4; rg++) {
        int row = row0 + wm * 128 + mt * 16 + l4 * 4 + rg;
        int cl = col0 + wn * 16 + ((nt >> 1) * 128) + ((nt & 1) * 64) + l15;
        float v = acc[mt][nt][rg];
        if (EPI == 2) {
          ((float*)C0)[(size_t)row * N + cl] = v;
        } else {
          if (cl < 3072) {
            int s = row & (SEQ - 1);
            float cc = ct[s * 64 + wn * 16 + l15];
            float ss = st[s * 64 + wn * 16 + l15];
            float pv = acc[mt][nt ^ 1][rg];
            v = (nt & 1) ? fmaf(v, cc, pv * ss) : fmaf(v, cc, -pv * ss);
          }
          if (cl < 2048) {
            v *= 1.7677669529663689e-3f;  // pre-scale Q by 1/(50*sqrt(128))
            ((bf16*)C0)[(size_t)row * 2048 + cl] = (bf16)v;
          } else if (cl < 3072) {
            ((bf16*)C1)[(size_t)row * 1024 + (cl - 2048)] = (bf16)v;
          } else {
            // V written directly transposed: VT[(b*8+kvh)*128+d][s]
            int vcol = cl - 3072;
            int kvh = vcol >> 7, d = vcol & 127;
            int bb = row >> 11, s = row & (SEQ - 1);
            ((bf16*)C2)[(((size_t)(bb * NKV + kvh) * HD) + d) * SEQ + s] = (bf16)v;
          }
        }
      }
}

// ================= 256x128 GEMM (Wo) — merged 1-phase/tile (unchanged) =================
__global__ __launch_bounds__(512, 2) void gemm2p(const bf16* __restrict__ A,
                                                 const bf16* __restrict__ BT,
                                                 float* __restrict__ C, int M, int N, int K) {
  __shared__ alignas(16) char ldsA[65536];  // [buf:2][half:2][128r][64k]
  __shared__ alignas(16) char ldsB[49152];  // [buf:3][128c][64k]
  const int tid = threadIdx.x, lane = tid & 63, w = tid >> 6;
  const int l15 = lane & 15, l4 = lane >> 4;
  const int wm = w >> 1, wn = w & 1;
  const int gx = gridDim.x;
  const int nwg = gx * gridDim.y;
  int id = blockIdx.y * gx + blockIdx.x;
  id = (id & 7) * (nwg >> 3) + (id >> 3);
  const int row0 = (id / gx) * 256;
  const int col0 = (id % gx) * 128;

  f32x4 acc[4][4];
#pragma unroll
  for (int mt = 0; mt < 4; mt++)
#pragma unroll
    for (int nt = 0; nt < 4; nt++) acc[mt][nt] = fzero4();

  const int rG0 = tid >> 3, sG0 = ((tid & 7) ^ (rG0 & 7)) * 8;
  const int ci1 = 512 + tid;
  const int rG1 = ci1 >> 3, sG1 = ((ci1 & 7) ^ (rG1 & 7)) * 8;
  const int dst0 = tid * 16, dst1 = (512 + tid) * 16;

  const bf16* Asrc = A + (size_t)row0 * K;
  const bf16* Bsrc = BT + (size_t)col0 * K;
  const int nk = K >> 6;

#define STG_A2(half, kt, buf)                                        \
  {                                                                  \
    char* d = ldsA + (buf) * 32768 + (half) * 16384;                 \
    const bf16* s = Asrc + (size_t)((half) * 128) * K + (kt) * 64;   \
    async16(d + dst0, s + (size_t)rG0 * K + sG0);                    \
    async16(d + dst1, s + (size_t)rG1 * K + sG1);                    \
  }
#define STG_B2(kt, buf)                                              \
  {                                                                  \
    char* d = ldsB + (buf) * 16384;                                  \
    const bf16* s = Bsrc + (kt) * 64;                                \
    async16(d + dst0, s + (size_t)rG0 * K + sG0);                    \
    async16(d + dst1, s + (size_t)rG1 * K + sG1);                    \
  }

  STG_B2(0, 0) STG_A2(0, 0, 0) STG_A2(1, 0, 0)
  STG_B2(1, 1) STG_A2(0, 1, 1) STG_A2(1, 1, 1)
  WAITV(6);
  BAR();

  bf16x8 af[8];
  bf16x8 bfr[8];

  for (int t = 0; t < nk; ++t) {
    const int abuf = t & 1;
    int bb = t % 3;
    const char* bA = ldsA + abuf * 32768 + (wm >> 1) * 16384;
    const char* bB = ldsB + bb * 16384;
    const bool s2 = (t + 2) < nk;
    int bb2 = bb + 2; if (bb2 >= 3) bb2 -= 3;

#pragma unroll
    for (int mt = 0; mt < 4; mt++)
#pragma unroll
      for (int kc = 0; kc < 2; kc++) {
        int r = (wm & 1) * 64 + mt * 16 + l15;
        int off = ((r << 7) + ((kc * 4 + l4) << 4)) ^ ((r & 7) << 4);
        af[mt * 2 + kc] = *(const bf16x8_a*)(bA + off);
      }
#pragma unroll
    for (int nt = 0; nt < 4; nt++)
#pragma unroll
      for (int kc = 0; kc < 2; kc++) {
        int c = wn * 16 + nt * 32 + l15;
        int off = ((c << 7) + ((kc * 4 + l4) << 4)) ^ ((c & 7) << 4);
        bfr[nt * 2 + kc] = *(const bf16x8_a*)(bB + off);
      }
    BAR();  // all waves' reads done -> safe to stage into abuf
    if (s2) { STG_B2(t + 2, bb2) STG_A2(0, t + 2, abuf) STG_A2(1, t + 2, abuf) }
    __builtin_amdgcn_s_setprio(1);
#pragma unroll
    for (int mt = 0; mt < 4; mt++)
#pragma unroll
      for (int nt = 0; nt < 4; nt++)
#pragma unroll
        for (int kc = 0; kc < 2; kc++)
          acc[mt][nt] = mfma16(af[mt * 2 + kc], bfr[nt * 2 + kc], acc[mt][nt]);
    __builtin_amdgcn_s_setprio(0);
    if (s2) { WAITV(6); } else { WAITV(0); }
    BAR();
  }
#undef STG_A2
#undef STG_B2

#pragma unroll
  for (int mt = 0; mt < 4; mt++)
#pragma unroll
    for (int nt = 0; nt < 4; nt++)
#pragma unroll
      for (int rg = 0; rg < 4; rg++) {
        int row = row0 + wm * 64 + mt * 16 + l4 * 4 + rg;
        int cl = col0 + wn * 16 + nt * 32 + l15;
        C[(size_t)row * N + cl] = acc[mt][nt][rg];
      }
}

// ========== Flash attention v10 (unchanged from R14, race-free) ==========
__global__ __launch_bounds__(512, 2) void attn10(const bf16* __restrict__ Q,
                                                 const bf16* __restrict__ Kg,
                                                 const bf16* __restrict__ VTg,
                                                 bf16* __restrict__ O) {
  __shared__ alignas(16) char ldsK[49152];   // 3 x [64 kv][128 d], 16-slot swizzle
  __shared__ alignas(16) char ldsV[49152];   // 3 x [128 d][64 kv], 8-slot swizzle
  const int tid = threadIdx.x, lane = tid & 63, w = tid >> 6;
  const int l31 = lane & 31, hl = lane >> 5;

  const int nx = gridDim.x, ny = gridDim.y;
  const int nwg = nx * ny * gridDim.z;  // 256
  int id = (blockIdx.z * ny + blockIdx.y) * nx + blockIdx.x;
  id = (id & 7) * (nwg >> 3) + (id >> 3);
  const int qt = id % nx; id /= nx;
  const int h = id % ny; const int b = id / ny;
  const int kvh = h >> 1;
  const int qrow = b * SEQ + qt * 256 + w * 32 + l31;

  bf16x8 qf[8];
  const bf16* qp = Q + (size_t)qrow * (NHEAD * HD) + h * HD + hl * 8;
#pragma unroll
  for (int kc = 0; kc < 8; kc++) qf[kc] = *(const bf16x8_a*)(qp + kc * 16);

  f32x16 oT[4];
#pragma unroll
  for (int dt = 0; dt < 4; dt++)
#pragma unroll
    for (int r = 0; r < 16; r++) oT[dt][r] = 0.f;
  f32x2 ls2; ls2[0] = 0.f; ls2[1] = 0.f;

  const int rK = tid >> 4, sK = (tid & 15) ^ (rK & 15);  // 16-slot swizzle
  const int rV = tid >> 3, sV = (tid & 7) ^ (rV & 7);    // 8-slot swizzle
  const size_t koff0 = (size_t)(b * SEQ + rK) * (NKV * HD) + kvh * HD + sK * 8;
  const size_t voff0 = ((size_t)(b * NKV + kvh) * HD + rV) * SEQ + sV * 8;

  const float Ac = 72.13475204444817f;    // 50*log2(e)
  const float Bc = -24.044917348149389f;  // Ac * (-1/3)

  auto STAGE = [&](int buf, int t) {
    char* dK = ldsK + buf * 16384;
    char* dV = ldsV + buf * 16384;
    const bf16* ks = Kg + koff0 + (size_t)t * (64 * NKV * HD);
    const bf16* vs = VTg + voff0 + (size_t)t * 64;
    async16(dK + tid * 16, ks);
    async16(dK + (512 + tid) * 16, ks + (size_t)32 * (NKV * HD));
    async16(dV + tid * 16, vs);
    async16(dV + (512 + tid) * 16, vs + (size_t)64 * SEQ);
  };

  const int kvr0 = l31, kvr1 = 32 + l31;

#define QKT(SC, lKp)                                                     \
  do {                                                                   \
    _Pragma("unroll")                                                    \
    for (int r = 0; r < 16; r++) { (SC)[0][r] = 0.f; (SC)[1][r] = 0.f; } \
    _Pragma("unroll")                                                    \
    for (int kc = 0; kc < 8; kc++) {                                     \
      int slot = kc * 2 + hl;                                            \
      int off0 = (kvr0 << 8) | ((slot ^ (kvr0 & 15)) << 4);              \
      int off1 = (kvr1 << 8) | ((slot ^ (kvr1 & 15)) << 4);              \
      bf16x8 kf0 = *(const bf16x8_a*)((lKp) + off0);                     \
      bf16x8 kf1 = *(const bf16x8_a*)((lKp) + off1);                     \
      (SC)[0] = mfma32(kf0, qf[kc], (SC)[0]);                            \
      (SC)[1] = mfma32(kf1, qf[kc], (SC)[1]);                            \
    }                                                                    \
  } while (0)

#define SOFTMAX(SC, PB)                                                  \
  do {                                                                   \
    _Pragma("unroll")                                                    \
    for (int ntb = 0; ntb < 2; ntb++) {                                  \
      uint u[4][2];                                                      \
      _Pragma("unroll")                                                  \
      for (int r2 = 0; r2 < 8; r2++) {                                   \
        f32x2 z; z[0] = (SC)[ntb][2 * r2]; z[1] = (SC)[ntb][2 * r2 + 1]; \
        f32x2 z2 = z * z;                                                \
        f32x2 wv = z2 * Bc + Ac;                                         \
        f32x2 e = z * wv;                                                \
        float p0 = ex2(e[0]), p1 = ex2(e[1]);                            \
        ls2[0] += p0; ls2[1] += p1;                                      \
        u[r2 >> 1][r2 & 1] = pkbf16(p0, p1);                             \
      }                                                                  \
      _Pragma("unroll")                                                  \
      for (int sub = 0; sub < 2; sub++) {                                \
        u32x2 r0 = pswap(u[2 * sub][0], u[2 * sub + 1][0]);              \
        u32x2 r1 = pswap(u[2 * sub][1], u[2 * sub + 1][1]);              \
        u32x4 bu;                                                        \
        bu[0] = r0[0];                                                   \
        bu[1] = r1[0];                                                   \
        bu[2] = r0[1];                                                   \
        bu[3] = r1[1];                                                   \
        (PB)[ntb * 2 + sub] = __builtin_bit_cast(bf16x8, bu);            \
      }                                                                  \
    }                                                                    \
  } while (0)

#define PVACC(PB, lVp)                                                   \
  do {                                                                   \
    _Pragma("unroll")                                                    \
    for (int kvb = 0; kvb < 4; kvb++) {                                  \
      int slot = kvb * 2 + hl;                                           \
      _Pragma("unroll")                                                  \
      for (int dt = 0; dt < 4; dt++) {                                   \
        int d = dt * 32 + l31;                                           \
        int off = (d << 7) | ((slot ^ (d & 7)) << 4);                    \
        bf16x8 vf = *(const bf16x8_a*)((lVp) + off);                     \
        oT[dt] = mfma32(vf, (PB)[kvb], oT[dt]);                          \
      }                                                                  \
    }                                                                    \
  } while (0)

  constexpr int NT = SEQ / 64;  // 32
  STAGE(0, 0);
  STAGE(1, 1);
  WAITV(4);  // tile 0 drained (tile 1's 4 may pend)
  BAR();     // cross-wave: tile 0 visible

  f32x16 scA[2], scB[2];
  bf16x8 pb[4];
  QKT(scA, ldsK);  // tile 0, buf 0

  for (int it = 0; it < NT / 2; ++it) {
    const int t0 = 2 * it;
    {
      const int t = t0;
      BAR();  // all waves' tile-(t-1) reads consumed -> safe to overwrite its buf
      if (t + 2 < NT) STAGE((t + 2) % 3, t + 2);
      SOFTMAX(scA, pb);
      if (t + 2 < NT) { WAITV(4); } else { WAITV(0); }  // drain tile t+1
      BAR();  // cross-wave: tile t+1 staged & visible
      __builtin_amdgcn_s_setprio(1);
      if (t + 1 < NT) QKT(scB, ldsK + ((t + 1) % 3) * 16384);
      PVACC(pb, ldsV + (t % 3) * 16384);
      __builtin_amdgcn_s_setprio(0);
    }
    {
      const int t = t0 + 1;
      BAR();
      if (t + 2 < NT) STAGE((t + 2) % 3, t + 2);
      SOFTMAX(scB, pb);
      if (t + 2 < NT) { WAITV(4); } else { WAITV(0); }
      BAR();
      __builtin_amdgcn_s_setprio(1);
      if (t + 1 < NT) QKT(scA, ldsK + ((t + 1) % 3) * 16384);
      PVACC(pb, ldsV + (t % 3) * 16384);
      __builtin_amdgcn_s_setprio(0);
    }
  }
#undef QKT
#undef SOFTMAX
#undef PVACC

  float lsum = ls2[0] + ls2[1];
  float lsf = lsum + __shfl_xor(lsum, 32);
  float inv = 1.0f / lsf;
  bf16* ob = O + (size_t)qrow * (NHEAD * HD) + h * HD;
#pragma unroll
  for (int dt = 0; dt < 4; dt++)
#pragma unroll
    for (int g = 0; g < 4; g++) {
      u32x2 pr;
      pr[0] = pkbf16(oT[dt][4 * g] * inv, oT[dt][4 * g + 1] * inv);
      pr[1] = pkbf16(oT[dt][4 * g + 2] * inv, oT[dt][4 * g + 3] * inv);
      *(u32x2_a*)(ob + dt * 32 + 8 * g + 4 * hl) = pr;
    }
}

extern "C" void kernel_launch(void* const* d_in, const int* in_sizes, int n_in,
                              void* d_out, int out_size, void* d_ws, size_t ws_size,
                              hipStream_t stream) {
  const float* X  = (const float*)d_in[0];
  const float* Wq = (const float*)d_in[1];
  const float* Wk = (const float*)d_in[2];
  const float* Wv = (const float*)d_in[3];
  const float* Wo = (const float*)d_in[4];
  float* out = (float*)d_out;

  char* ws = (char*)d_ws;
  size_t off = 0;
  auto alloc = [&](size_t bytes) {
    void* p = ws + off;
    off += (bytes + 255) & ~(size_t)255;
    return p;
  };
  bf16* Xb  = (bf16*)alloc((size_t)MROWS * HID * 2);
  // WqT/WkT/WvT adjacent & contiguous -> fused BT [4096][2048]
  bf16* WqT = (bf16*)alloc((size_t)2048 * 2048 * 2);
  bf16* WkT = (bf16*)alloc((size_t)1024 * 2048 * 2);
  bf16* WvT = (bf16*)alloc((size_t)1024 * 2048 * 2);
  bf16* WoT = (bf16*)alloc((size_t)2048 * 2048 * 2);
  bf16* Qb  = (bf16*)alloc((size_t)MROWS * 2048 * 2);
  bf16* Kb  = (bf16*)alloc((size_t)MROWS * 1024 * 2);
  bf16* VTb = (bf16*)alloc((size_t)16 * 128 * 2048 * 2);
  bf16* AOb = (bf16*)alloc((size_t)MROWS * 2048 * 2);
  float* ct = (float*)alloc((size_t)SEQ * 64 * 4);
  float* st = (float*)alloc((size_t)SEQ * 64 * 4);

  prep<<<dim3(32, 32, 6), 256, 0, stream>>>(X, Wq, Wk, Wv, Wo, Xb, WqT, WkT, WvT, WoT, ct, st);
  gemm8p<1><<<dim3(16, 16), 512, 0, stream>>>(Xb, WqT, Qb, Kb, VTb, MROWS, 4096, 2048, ct, st);
  attn10<<<dim3(8, 16, 2), 512, 0, stream>>>(Qb, Kb, VTb, AOb);
  gemm2p<<<dim3(16, 16), 512, 0, stream>>>(AOb, WoT, out, MROWS, 2048, 2048);

  (void)in_sizes; (void)n_in; (void)out_size; (void)ws_size;
}